// Round 4
// baseline (127.302 us; speedup 1.0000x reference)
//
#include <hip/hip_runtime.h>

typedef _Float16 half8 __attribute__((ext_vector_type(8)));
typedef _Float16 half4v __attribute__((ext_vector_type(4)));
typedef float f32x4 __attribute__((ext_vector_type(4)));

// Problem sizes (fixed): B=8, S=512, D=1024, H=16, HD=64; M = B*S = 4096
#define OFF_CS    0u
#define OFF_XH    (1u<<20)
#define OFF_WQKVT (OFF_XH + 8u*1024u*1024u)
#define OFF_WOT   (OFF_WQKVT + 8u*1024u*1024u)
#define OFF_QKV   (OFF_WOT + 2u*1024u*1024u)
#define OFF_VT    OFF_XH
#define OFF_ATTN  OFF_WQKVT

__device__ __forceinline__ void gload16(const _Float16* g, _Float16* l) {
  __builtin_amdgcn_global_load_lds((const __attribute__((address_space(1))) void*)g,
                                   (__attribute__((address_space(3))) void*)l, 16, 0, 0);
}

__device__ __forceinline__ void phase_bar() {
  __builtin_amdgcn_sched_barrier(0);
  asm volatile("s_barrier" ::: "memory");
  __builtin_amdgcn_sched_barrier(0);
}

// ---- packed RoPE table: cs[pos*32+j] = (cos, sin) ----
__global__ void rope_table_k(float2* __restrict__ cs) {
  int idx = blockIdx.x * 256 + threadIdx.x;
  if (idx >= 512 * 32) return;
  int pos = idx >> 5, j = idx & 31;
  float inv = powf(10000.0f, -(float)j * (1.0f / 32.0f));
  float f = (float)pos * inv;
  cs[idx] = make_float2(cosf(f), sinf(f));
}

// ---- fp32 -> fp16 convert ----
__global__ void convert_f16_k(const float* __restrict__ in, _Float16* __restrict__ out, int n4) {
  int i = blockIdx.x * 256 + threadIdx.x;
  if (i >= n4) return;
  float4 v = ((const float4*)in)[i];
  half4v h;
  h[0] = (_Float16)v.x; h[1] = (_Float16)v.y; h[2] = (_Float16)v.z; h[3] = (_Float16)v.w;
  *(half4v*)(out + (size_t)i * 4) = h;
}

// ---- 4 weight transposes in one launch: W [k][n] f32 -> Wt [n][k] f16 ----
__global__ void transpose4_k(const float* __restrict__ W0, const float* __restrict__ W1,
                             const float* __restrict__ W2, const float* __restrict__ W3,
                             _Float16* __restrict__ dqkv, _Float16* __restrict__ dwo) {
  __shared__ float tile[32][33];
  int z = blockIdx.z;
  const float* W = z == 0 ? W0 : z == 1 ? W1 : z == 2 ? W2 : W3;
  _Float16* Wt = z < 3 ? dqkv + (size_t)z * 1048576 : dwo;
  int tx = threadIdx.x, ty = threadIdx.y;
  int bx = blockIdx.x, by = blockIdx.y;
#pragma unroll
  for (int i = 0; i < 4; i++)
    tile[ty + i * 8][tx] = W[(size_t)(by * 32 + ty + i * 8) * 1024 + bx * 32 + tx];
  __syncthreads();
#pragma unroll
  for (int i = 0; i < 4; i++)
    Wt[(size_t)(bx * 32 + ty + i * 8) * 1024 + by * 32 + tx] = (_Float16)tile[tx][ty + i * 8];
}

// ================= 256x256 8-phase GEMM (QKV + fused RoPE) =================
// C[4096 x 3072] = fp16round(A[4096x1024] @ Bt[3072x1024]^T + bias), RoPE on q,k cols.
// 8 waves (2M x 4N), BK=64, double-buffered 128 KiB LDS, T2 XOR-swizzle,
// quad-top prefetch of next K-tile, vmcnt(0) only at quad close, setprio MFMA clusters.
__device__ __forceinline__ void stage_tile(const _Float16* Ag, const _Float16* Bg,
                                           _Float16* Al, _Float16* Bl, int w, int lane) {
  int srow = lane >> 3;
  int scol = ((lane & 7) ^ srow) * 8;  // inverse-swizzled global source (rule 21)
#pragma unroll
  for (int rr = 0; rr < 4; rr++) {
    int row = rr * 64 + w * 8 + srow;
    gload16(Ag + (size_t)row * 1024 + scol, Al + (rr * 64 + w * 8) * 64);
    gload16(Bg + (size_t)row * 1024 + scol, Bl + (rr * 64 + w * 8) * 64);
  }
}

__global__ __launch_bounds__(512, 2) void gemm256_k(
    const _Float16* __restrict__ A, const _Float16* __restrict__ Bt,
    const float* __restrict__ b0, const float* __restrict__ b1, const float* __restrict__ b2,
    _Float16* __restrict__ C, const float2* __restrict__ cs) {
  __shared__ _Float16 Ab[2][256 * 64];
  __shared__ _Float16 Bb[2][256 * 64];

  int bid = blockIdx.x;                       // 0..191
  int wgid = (bid & 7) * 24 + (bid >> 3);     // XCD-chunked (192 % 8 == 0 -> bijective)
  int by = wgid / 12, bx = wgid % 12;

  int tid = threadIdx.x, lane = tid & 63, w = tid >> 6;
  int wr = w >> 2, wc = w & 3;
  int arow = lane & 15, ag = lane >> 4;
  int rs = arow & 7;
  int slot0 = ag ^ rs, slot1 = (4 + ag) ^ rs;  // swizzled 16B-slot per k-slice

  const _Float16* Agt = A + (size_t)(by * 256) * 1024;
  const _Float16* Bgt = Bt + (size_t)(bx * 256) * 1024;

  f32x4 acc[8][4] = {};

  // prologue: stage K-tile 0 -> buf0
  stage_tile(Agt, Bgt, &Ab[0][0], &Bb[0][0], w, lane);
  asm volatile("s_waitcnt vmcnt(0)" ::: "memory");
  phase_bar();

  for (int t = 0; t < 16; t++) {
    const _Float16* Ac = &Ab[t & 1][0];
    const _Float16* Bc = &Bb[t & 1][0];
    // quad-top: prefetch K-tile t+1 into the other buffer (its old reads are 1 quad behind a barrier)
    if (t < 15)
      stage_tile(Agt + (t + 1) * 64, Bgt + (t + 1) * 64,
                 &Ab[(t + 1) & 1][0], &Bb[(t + 1) & 1][0], w, lane);
    half8 bfr[4][2];
#pragma unroll
    for (int p = 0; p < 4; p++) {
      if (p == 0) {
#pragma unroll
        for (int n = 0; n < 4; n++) {
          int R = wc * 64 + n * 16 + arow;
          bfr[n][0] = *(const half8*)&Bc[R * 64 + slot0 * 8];
          bfr[n][1] = *(const half8*)&Bc[R * 64 + slot1 * 8];
        }
      }
      half8 afr[2][2];
#pragma unroll
      for (int ml = 0; ml < 2; ml++) {
        int R = wr * 128 + (2 * p + ml) * 16 + arow;
        afr[ml][0] = *(const half8*)&Ac[R * 64 + slot0 * 8];
        afr[ml][1] = *(const half8*)&Ac[R * 64 + slot1 * 8];
      }
      phase_bar();
      __builtin_amdgcn_s_setprio(1);
#pragma unroll
      for (int ml = 0; ml < 2; ml++)
#pragma unroll
        for (int n = 0; n < 4; n++) {
          acc[2 * p + ml][n] =
              __builtin_amdgcn_mfma_f32_16x16x32_f16(afr[ml][0], bfr[n][0], acc[2 * p + ml][n], 0, 0, 0);
          acc[2 * p + ml][n] =
              __builtin_amdgcn_mfma_f32_16x16x32_f16(afr[ml][1], bfr[n][1], acc[2 * p + ml][n], 0, 0, 0);
        }
      __builtin_amdgcn_s_setprio(0);
      if (p == 3) asm volatile("s_waitcnt vmcnt(0)" ::: "memory");  // next K-tile landed
      phase_bar();
    }
  }

  // ---- epilogue: bias + fp16 round (+ RoPE for q,k cols) ----
  int gc0 = bx * 256 + wc * 64;  // 64-aligned: wave entirely inside one q/k/v head-block
  const float* bp = gc0 < 1024 ? b0 : (gc0 < 2048 ? b1 : b2);
  float bb_[4];
#pragma unroll
  for (int n = 0; n < 4; n++) bb_[n] = bp[(gc0 & 1023) + n * 16 + arow];

  if (gc0 < 2048) {
    bool isQ = gc0 < 1024;
#pragma unroll
    for (int m = 0; m < 8; m++) {
      int gr = by * 256 + wr * 128 + m * 16 + ag * 4;
#pragma unroll
      for (int r = 0; r < 4; r++) {
        int row = gr + r, pos = row & 511;
#pragma unroll
        for (int n = 0; n < 2; n++) {
          int j = n * 16 + arow;
          float a = (float)(_Float16)(acc[m][n][r] + bb_[n]);
          float b = (float)(_Float16)(acc[m][n + 2][r] + bb_[n + 2]);
          float2 tt = cs[pos * 32 + j];
          float o0 = a * tt.x - b * tt.y;
          float o1 = b * tt.x + a * tt.y;
          if (isQ) { o0 *= 0.015625f; o1 *= 0.015625f; }  // scale^2 = 1/HD
          C[(size_t)row * 3072 + gc0 + j]      = (_Float16)o0;
          C[(size_t)row * 3072 + gc0 + j + 32] = (_Float16)o1;
        }
      }
    }
  } else {
#pragma unroll
    for (int m = 0; m < 8; m++) {
      int gr = by * 256 + wr * 128 + m * 16 + ag * 4;
#pragma unroll
      for (int n = 0; n < 4; n++)
#pragma unroll
        for (int r = 0; r < 4; r++)
          C[(size_t)(gr + r) * 3072 + gc0 + n * 16 + arow] = (_Float16)(acc[m][n][r] + bb_[n]);
    }
  }
}

// ---- output-proj GEMM (m97 structure): C_f32[4096x1024] = fp16round(A @ Wot^T + bo) ----
__global__ __launch_bounds__(256, 2) void gemm_out_k(
    const _Float16* __restrict__ A, const _Float16* __restrict__ Bt,
    const float* __restrict__ bo, float* __restrict__ Cv) {
  __shared__ _Float16 As[128 * 32];
  __shared__ _Float16 Bs[128 * 32];
  const int K = 1024, N = 1024;
  int bx = blockIdx.x, by = blockIdx.y;
  int tid = threadIdx.x, lane = tid & 63, w = tid >> 6;
  int wr = w >> 1, wc = w & 1;
  int arow = lane & 15, ag = lane >> 4;
  int lr = lane >> 2, lc = lane & 3;

  f32x4 acc[4][4] = {};

  for (int kt = 0; kt < 32; ++kt) {
    int k0 = kt * 32;
#pragma unroll
    for (int i = 0; i < 2; i++) {
      gload16(A  + (size_t)(by * 128 + w * 32 + i * 16 + lr) * K + k0 + lc * 8,
              &As[(w * 32 + i * 16) * 32]);
      gload16(Bt + (size_t)(bx * 128 + w * 32 + i * 16 + lr) * K + k0 + lc * 8,
              &Bs[(w * 32 + i * 16) * 32]);
    }
    __syncthreads();
    half8 a[4], b[4];
#pragma unroll
    for (int mi = 0; mi < 4; mi++)
      a[mi] = *(const half8*)&As[(wr * 64 + mi * 16 + arow) * 32 + ag * 8];
#pragma unroll
    for (int ni = 0; ni < 4; ni++)
      b[ni] = *(const half8*)&Bs[(wc * 64 + ni * 16 + arow) * 32 + ag * 8];
#pragma unroll
    for (int mi = 0; mi < 4; mi++)
#pragma unroll
      for (int ni = 0; ni < 4; ni++)
        acc[mi][ni] = __builtin_amdgcn_mfma_f32_16x16x32_f16(a[mi], b[ni], acc[mi][ni], 0, 0, 0);
    __syncthreads();
  }

#pragma unroll
  for (int mi = 0; mi < 4; mi++) {
    int gr = by * 128 + wr * 64 + mi * 16 + ag * 4;
#pragma unroll
    for (int ni = 0; ni < 4; ni++) {
      int gc = bx * 128 + wc * 64 + ni * 16 + arow;
      float bb = bo[gc];
#pragma unroll
      for (int r = 0; r < 4; r++)
        Cv[(size_t)(gr + r) * N + gc] = (float)(_Float16)(acc[mi][ni][r] + bb);
    }
  }
}

// ---- V^T gather: qkv V-part -> VT[bh][hd][s] ----
__global__ void vt_k(const _Float16* __restrict__ qkv, _Float16* __restrict__ VT) {
  int id = blockIdx.x;           // 2048 blocks; id%8 = bh%8 -> XCD-grouped
  int bh = id & 127, r4 = id >> 7;
  int b = bh >> 4, h = bh & 15;
  int lane = threadIdx.x & 63, w = threadIdx.x >> 6;
  int hd = r4 * 4 + w;
  const _Float16* src = qkv + (size_t)(b * 512 + lane * 8) * 3072 + 2048 + h * 64 + hd;
  half8 v;
#pragma unroll
  for (int j = 0; j < 8; j++) v[j] = src[(size_t)j * 3072];
  *(half8*)(VT + ((size_t)bh * 64 + hd) * 512 + lane * 8) = v;
}

// ---- Fused attention (round-3 version, unchanged) ----
__global__ __launch_bounds__(256, 4) void attn_k(const _Float16* __restrict__ qkv,
                                                 const _Float16* __restrict__ VT,
                                                 _Float16* __restrict__ out) {
  int id = blockIdx.x;
  int bh = id & 127, qt = id >> 7;
  int b = bh >> 4, h = bh & 15;
  int tid = threadIdx.x, lane = tid & 63, w = tid >> 6;
  int arow = lane & 15, ag = lane >> 4;

  __shared__ _Float16 Ks[64 * 64];
  __shared__ _Float16 Vs[64 * 64];
  __shared__ _Float16 Pl[4][16][72];

  int qrow0 = b * 512 + qt * 64 + w * 16;
  const _Float16* Qp = qkv + (size_t)qrow0 * 3072 + h * 64;
  half8 qa[2];
#pragma unroll
  for (int ks = 0; ks < 2; ks++)
    qa[ks] = *(const half8*)(Qp + (size_t)arow * 3072 + ks * 32 + ag * 8);

  const _Float16* Kb = qkv + (size_t)(b * 512) * 3072 + 1024 + h * 64;
  const _Float16* Vb = VT + (size_t)bh * 64 * 512;

  int srow = lane >> 3;
  int sslot = (lane & 7) ^ srow;
  const _Float16* Ksrc0 = Kb + (size_t)(w * 16 + srow) * 3072 + sslot * 8;
  const _Float16* Vsrc0 = Vb + (size_t)(w * 16 + srow) * 512 + sslot * 8;

  int rs = arow & 7;

  float psl[4] = {0.f, 0.f, 0.f, 0.f};
  f32x4 oacc[4] = {};

  for (int st = 0; st < 8; ++st) {
#pragma unroll
    for (int i = 0; i < 2; i++) {
      gload16(Ksrc0 + (size_t)(st * 64 + i * 8) * 3072, &Ks[(w * 16 + i * 8) * 64]);
      gload16(Vsrc0 + (size_t)(i * 8) * 512 + st * 64,  &Vs[(w * 16 + i * 8) * 64]);
    }
    __syncthreads();

    f32x4 lg[4];
#pragma unroll
    for (int c = 0; c < 4; c++) {
      f32x4 a0 = {};
#pragma unroll
      for (int ks = 0; ks < 2; ks++) {
        int slot = (ks * 4 + ag) ^ rs;
        half8 kb = *(const half8*)&Ks[(c * 16 + arow) * 64 + slot * 8];
        a0 = __builtin_amdgcn_mfma_f32_16x16x32_f16(qa[ks], kb, a0, 0, 0, 0);
      }
      lg[c] = a0;
    }
    _Float16 ph[4][4];
#pragma unroll
    for (int r = 0; r < 4; r++) {
#pragma unroll
      for (int c = 0; c < 4; c++) {
        float p = __builtin_amdgcn_exp2f(lg[c][r] * 1.44269504f);
        psl[r] += p;
        ph[c][r] = (_Float16)p;
      }
    }
#pragma unroll
    for (int c = 0; c < 4; c++)
#pragma unroll
      for (int r = 0; r < 4; r++) Pl[w][ag * 4 + r][c * 16 + arow] = ph[c][r];
#pragma unroll
    for (int ks = 0; ks < 2; ks++) {
      half8 pa = *(const half8*)&Pl[w][arow][ks * 32 + ag * 8];
#pragma unroll
      for (int c = 0; c < 4; c++) {
        int slot = (ks * 4 + ag) ^ rs;
        half8 vb = *(const half8*)&Vs[(c * 16 + arow) * 64 + slot * 8];
        oacc[c] = __builtin_amdgcn_mfma_f32_16x16x32_f16(pa, vb, oacc[c], 0, 0, 0);
      }
    }
    __syncthreads();
  }
#pragma unroll
  for (int r = 0; r < 4; r++)
#pragma unroll
    for (int d = 1; d < 16; d <<= 1) psl[r] += __shfl_xor(psl[r], d, 16);
#pragma unroll
  for (int c = 0; c < 4; c++)
#pragma unroll
    for (int r = 0; r < 4; r++) {
      float v = oacc[c][r] / psl[r];
      out[(size_t)(qrow0 + ag * 4 + r) * 1024 + h * 64 + c * 16 + arow] = (_Float16)v;
    }
}

extern "C" void kernel_launch(void* const* d_in, const int* in_sizes, int n_in,
                              void* d_out, int out_size, void* d_ws, size_t ws_size,
                              hipStream_t stream) {
  const float* x  = (const float*)d_in[0];
  const float* Wq = (const float*)d_in[1];
  const float* bq = (const float*)d_in[2];
  const float* Wk = (const float*)d_in[3];
  const float* bk = (const float*)d_in[4];
  const float* Wv = (const float*)d_in[5];
  const float* bv = (const float*)d_in[6];
  const float* Wo = (const float*)d_in[7];
  const float* bo = (const float*)d_in[8];

  char* ws = (char*)d_ws;
  float2* cs      = (float2*)(ws + OFF_CS);
  _Float16* xh    = (_Float16*)(ws + OFF_XH);
  _Float16* wqkvt = (_Float16*)(ws + OFF_WQKVT);
  _Float16* wot   = (_Float16*)(ws + OFF_WOT);
  _Float16* qkv   = (_Float16*)(ws + OFF_QKV);
  _Float16* VT    = (_Float16*)(ws + OFF_VT);
  _Float16* attn  = (_Float16*)(ws + OFF_ATTN);

  rope_table_k<<<64, 256, 0, stream>>>(cs);
  convert_f16_k<<<4096, 256, 0, stream>>>(x, xh, 1048576);
  transpose4_k<<<dim3(32, 32, 4), dim3(32, 8), 0, stream>>>(Wq, Wk, Wv, Wo, wqkvt, wot);
  // qkv = fp16(x @ [Wq|Wk|Wv] + b), rope fused on q,k (q also x scale^2)
  gemm256_k<<<192, 512, 0, stream>>>(xh, wqkvt, bq, bk, bv, qkv, cs);
  vt_k<<<2048, 256, 0, stream>>>(qkv, VT);
  attn_k<<<1024, 256, 0, stream>>>(qkv, VT, attn);
  gemm_out_k<<<dim3(8, 32), 256, 0, stream>>>(attn, wot, bo, (float*)d_out);
}

// Round 5
// 118.199 us; speedup vs baseline: 1.0770x; 1.0770x over previous
//
#include <hip/hip_runtime.h>

typedef _Float16 half8 __attribute__((ext_vector_type(8)));
typedef _Float16 half4v __attribute__((ext_vector_type(4)));
typedef float f32x4 __attribute__((ext_vector_type(4)));

// Problem sizes (fixed): B=8, S=512, D=1024, H=16, HD=64; M = B*S = 4096
#define OFF_CS    0u
#define OFF_XH    (1u<<20)
#define OFF_WQKVT (OFF_XH + 8u*1024u*1024u)
#define OFF_WOT   (OFF_WQKVT + 8u*1024u*1024u)
#define OFF_QKV   (OFF_WOT + 2u*1024u*1024u)
#define OFF_VT    OFF_XH
#define OFF_ATTN  OFF_WQKVT

__device__ __forceinline__ void gload16(const _Float16* g, _Float16* l) {
  __builtin_amdgcn_global_load_lds((const __attribute__((address_space(1))) void*)g,
                                   (__attribute__((address_space(3))) void*)l, 16, 0, 0);
}

// ---- packed RoPE table: cs[pos*32+j] = (cos, sin) ----
__global__ void rope_table_k(float2* __restrict__ cs) {
  int idx = blockIdx.x * 256 + threadIdx.x;
  if (idx >= 512 * 32) return;
  int pos = idx >> 5, j = idx & 31;
  float inv = powf(10000.0f, -(float)j * (1.0f / 32.0f));
  float f = (float)pos * inv;
  cs[idx] = make_float2(cosf(f), sinf(f));
}

// ---- fp32 -> fp16 convert ----
__global__ void convert_f16_k(const float* __restrict__ in, _Float16* __restrict__ out, int n4) {
  int i = blockIdx.x * 256 + threadIdx.x;
  if (i >= n4) return;
  float4 v = ((const float4*)in)[i];
  half4v h;
  h[0] = (_Float16)v.x; h[1] = (_Float16)v.y; h[2] = (_Float16)v.z; h[3] = (_Float16)v.w;
  *(half4v*)(out + (size_t)i * 4) = h;
}

// ---- 4 weight transposes in one launch: W [k][n] f32 -> Wt [n][k] f16 ----
__global__ void transpose4_k(const float* __restrict__ W0, const float* __restrict__ W1,
                             const float* __restrict__ W2, const float* __restrict__ W3,
                             _Float16* __restrict__ dqkv, _Float16* __restrict__ dwo) {
  __shared__ float tile[32][33];
  int z = blockIdx.z;
  const float* W = z == 0 ? W0 : z == 1 ? W1 : z == 2 ? W2 : W3;
  _Float16* Wt = z < 3 ? dqkv + (size_t)z * 1048576 : dwo;
  int tx = threadIdx.x, ty = threadIdx.y;
  int bx = blockIdx.x, by = blockIdx.y;
#pragma unroll
  for (int i = 0; i < 4; i++)
    tile[ty + i * 8][tx] = W[(size_t)(by * 32 + ty + i * 8) * 1024 + bx * 32 + tx];
  __syncthreads();
#pragma unroll
  for (int i = 0; i < 4; i++)
    Wt[(size_t)(bx * 32 + ty + i * 8) * 1024 + by * 32 + tx] = (_Float16)tile[tx][ty + i * 8];
}

// ================= 256x256 ring-4 counted-vmcnt GEMM (QKV + fused RoPE) =================
// C[4096 x 3072] = fp16round(A[4096x1024] @ Bt[3072x1024]^T + bias), RoPE on q,k cols.
// BK=32, ring of 4 K-tiles (128 KiB LDS), prefetch depth 3, vmcnt(8) counted (never 0
// in main loop), ONE barrier + 32 MFMA per K-tile per wave, setprio, row-pair XOR swizzle.
// LDS layout per tile: row r, 16B-slot s at byte (r>>1)*128 + s8*16, s8=((r&1)*4+s)^((r>>1)&7).
// 64-lane frag read is a bijection over 8 rowpairs x 8 slots -> conflict-free.
__device__ __forceinline__ void stage_ring(const _Float16* Ag, const _Float16* Bg,
                                           _Float16* Al, _Float16* Bl, int w, int lane) {
  // linear LDS dest (chunk c = 1KB = 16 rows); source pre-applies inverse swizzle
  int q = (lane & 7) ^ (lane >> 3);
  int rloc = ((lane >> 3) << 1) + (q >> 2);  // row within 16-row chunk
  int gcol = (q & 3) * 8;                    // element column (slot*8)
#pragma unroll
  for (int i = 0; i < 2; i++) {
    int c = i * 8 + w;                       // chunk 0..15 -> rows c*16..+15
    gload16(Ag + (size_t)(c * 16 + rloc) * 1024 + gcol, Al + c * 512);
    gload16(Bg + (size_t)(c * 16 + rloc) * 1024 + gcol, Bl + c * 512);
  }
}

__global__ __launch_bounds__(512, 2) void gemm256_k(
    const _Float16* __restrict__ A, const _Float16* __restrict__ Bt,
    const float* __restrict__ b0, const float* __restrict__ b1, const float* __restrict__ b2,
    _Float16* __restrict__ C, const float2* __restrict__ cs) {
  __shared__ _Float16 Ar[4][256 * 32];  // 64 KiB
  __shared__ _Float16 Br[4][256 * 32];  // 64 KiB

  int bid = blockIdx.x;                       // 0..191
  int wgid = (bid & 7) * 24 + (bid >> 3);     // XCD-chunked (192 % 8 == 0 -> bijective)
  int by = wgid / 12, bx = wgid % 12;

  int tid = threadIdx.x, lane = tid & 63, w = tid >> 6;
  int wr = w >> 2, wc = w & 3;                // 2M x 4N waves; per-wave out 128x64
  int arow = lane & 15, ag = lane >> 4;       // frag row / k-slot
  int s8 = (((arow & 1) << 2) | ag) ^ ((arow >> 1) & 7);  // swizzled slot (wave-invariant)

  const _Float16* Agt = A + (size_t)(by * 256) * 1024;
  const _Float16* Bgt = Bt + (size_t)(bx * 256) * 1024;

  f32x4 acc[8][4] = {};

  // prologue: stage tiles 0,1,2
  stage_ring(Agt, Bgt, &Ar[0][0], &Br[0][0], w, lane);
  stage_ring(Agt + 32, Bgt + 32, &Ar[1][0], &Br[1][0], w, lane);
  stage_ring(Agt + 64, Bgt + 64, &Ar[2][0], &Br[2][0], w, lane);

  for (int t = 0; t < 32; ++t) {
    if (t < 30)       asm volatile("s_waitcnt vmcnt(8)" ::: "memory");  // tile t landed; t+1,t+2 fly
    else if (t == 30) asm volatile("s_waitcnt vmcnt(4)" ::: "memory");
    else              asm volatile("s_waitcnt vmcnt(0)" ::: "memory");
    asm volatile("s_barrier" ::: "memory");   // tile t visible; WAR for slot (t+3)&3 cleared

    const _Float16* Ac = &Ar[t & 3][0];
    const _Float16* Bc = &Br[t & 3][0];
    half8 af[8], bf[4];
#pragma unroll
    for (int m = 0; m < 8; m++) {
      int R = wr * 128 + m * 16 + arow;
      af[m] = *(const half8*)&Ac[(R >> 1) * 64 + s8 * 8];
    }
#pragma unroll
    for (int n = 0; n < 4; n++) {
      int R = wc * 64 + n * 16 + arow;
      bf[n] = *(const half8*)&Bc[(R >> 1) * 64 + s8 * 8];
    }
    if (t < 29)
      stage_ring(Agt + (t + 3) * 32, Bgt + (t + 3) * 32,
                 &Ar[(t + 3) & 3][0], &Br[(t + 3) & 3][0], w, lane);
    __builtin_amdgcn_s_setprio(1);
#pragma unroll
    for (int m = 0; m < 8; m++)
#pragma unroll
      for (int n = 0; n < 4; n++)
        acc[m][n] = __builtin_amdgcn_mfma_f32_16x16x32_f16(af[m], bf[n], acc[m][n], 0, 0, 0);
    __builtin_amdgcn_s_setprio(0);
  }

  // ---- epilogue: bias + fp16 round (+ RoPE for q,k cols) ----
  int gc0 = bx * 256 + wc * 64;  // 64-aligned: wave entirely inside one q/k/v head-block
  const float* bp = gc0 < 1024 ? b0 : (gc0 < 2048 ? b1 : b2);
  float bb_[4];
#pragma unroll
  for (int n = 0; n < 4; n++) bb_[n] = bp[(gc0 & 1023) + n * 16 + arow];

  if (gc0 < 2048) {
    bool isQ = gc0 < 1024;
#pragma unroll
    for (int m = 0; m < 8; m++) {
      int gr = by * 256 + wr * 128 + m * 16 + ag * 4;
#pragma unroll
      for (int r = 0; r < 4; r++) {
        int row = gr + r, pos = row & 511;
#pragma unroll
        for (int n = 0; n < 2; n++) {
          int j = n * 16 + arow;
          float a = (float)(_Float16)(acc[m][n][r] + bb_[n]);
          float b = (float)(_Float16)(acc[m][n + 2][r] + bb_[n + 2]);
          float2 tt = cs[pos * 32 + j];
          float o0 = a * tt.x - b * tt.y;
          float o1 = b * tt.x + a * tt.y;
          if (isQ) { o0 *= 0.015625f; o1 *= 0.015625f; }  // scale^2 = 1/HD
          C[(size_t)row * 3072 + gc0 + j]      = (_Float16)o0;
          C[(size_t)row * 3072 + gc0 + j + 32] = (_Float16)o1;
        }
      }
    }
  } else {
#pragma unroll
    for (int m = 0; m < 8; m++) {
      int gr = by * 256 + wr * 128 + m * 16 + ag * 4;
#pragma unroll
      for (int n = 0; n < 4; n++)
#pragma unroll
        for (int r = 0; r < 4; r++)
          C[(size_t)(gr + r) * 3072 + gc0 + n * 16 + arow] = (_Float16)(acc[m][n][r] + bb_[n]);
    }
  }
}

// ---- output-proj GEMM (m97 structure): C_f32[4096x1024] = fp16round(A @ Wot^T + bo) ----
__global__ __launch_bounds__(256, 2) void gemm_out_k(
    const _Float16* __restrict__ A, const _Float16* __restrict__ Bt,
    const float* __restrict__ bo, float* __restrict__ Cv) {
  __shared__ _Float16 As[128 * 32];
  __shared__ _Float16 Bs[128 * 32];
  const int K = 1024, N = 1024;
  int bx = blockIdx.x, by = blockIdx.y;
  int tid = threadIdx.x, lane = tid & 63, w = tid >> 6;
  int wr = w >> 1, wc = w & 1;
  int arow = lane & 15, ag = lane >> 4;
  int lr = lane >> 2, lc = lane & 3;

  f32x4 acc[4][4] = {};

  for (int kt = 0; kt < 32; ++kt) {
    int k0 = kt * 32;
#pragma unroll
    for (int i = 0; i < 2; i++) {
      gload16(A  + (size_t)(by * 128 + w * 32 + i * 16 + lr) * K + k0 + lc * 8,
              &As[(w * 32 + i * 16) * 32]);
      gload16(Bt + (size_t)(bx * 128 + w * 32 + i * 16 + lr) * K + k0 + lc * 8,
              &Bs[(w * 32 + i * 16) * 32]);
    }
    __syncthreads();
    half8 a[4], b[4];
#pragma unroll
    for (int mi = 0; mi < 4; mi++)
      a[mi] = *(const half8*)&As[(wr * 64 + mi * 16 + arow) * 32 + ag * 8];
#pragma unroll
    for (int ni = 0; ni < 4; ni++)
      b[ni] = *(const half8*)&Bs[(wc * 64 + ni * 16 + arow) * 32 + ag * 8];
#pragma unroll
    for (int mi = 0; mi < 4; mi++)
#pragma unroll
      for (int ni = 0; ni < 4; ni++)
        acc[mi][ni] = __builtin_amdgcn_mfma_f32_16x16x32_f16(a[mi], b[ni], acc[mi][ni], 0, 0, 0);
    __syncthreads();
  }

#pragma unroll
  for (int mi = 0; mi < 4; mi++) {
    int gr = by * 128 + wr * 64 + mi * 16 + ag * 4;
#pragma unroll
    for (int ni = 0; ni < 4; ni++) {
      int gc = bx * 128 + wc * 64 + ni * 16 + arow;
      float bb = bo[gc];
#pragma unroll
      for (int r = 0; r < 4; r++)
        Cv[(size_t)(gr + r) * N + gc] = (float)(_Float16)(acc[mi][ni][r] + bb);
    }
  }
}

// ---- V^T gather: qkv V-part -> VT[bh][hd][s] ----
__global__ void vt_k(const _Float16* __restrict__ qkv, _Float16* __restrict__ VT) {
  int id = blockIdx.x;           // 2048 blocks; id%8 = bh%8 -> XCD-grouped
  int bh = id & 127, r4 = id >> 7;
  int b = bh >> 4, h = bh & 15;
  int lane = threadIdx.x & 63, w = threadIdx.x >> 6;
  int hd = r4 * 4 + w;
  const _Float16* src = qkv + (size_t)(b * 512 + lane * 8) * 3072 + 2048 + h * 64 + hd;
  half8 v;
#pragma unroll
  for (int j = 0; j < 8; j++) v[j] = src[(size_t)j * 3072];
  *(half8*)(VT + ((size_t)bh * 64 + hd) * 512 + lane * 8) = v;
}

// ---- Fused attention (round-3 version, unchanged) ----
__global__ __launch_bounds__(256, 4) void attn_k(const _Float16* __restrict__ qkv,
                                                 const _Float16* __restrict__ VT,
                                                 _Float16* __restrict__ out) {
  int id = blockIdx.x;
  int bh = id & 127, qt = id >> 7;
  int b = bh >> 4, h = bh & 15;
  int tid = threadIdx.x, lane = tid & 63, w = tid >> 6;
  int arow = lane & 15, ag = lane >> 4;

  __shared__ _Float16 Ks[64 * 64];
  __shared__ _Float16 Vs[64 * 64];
  __shared__ _Float16 Pl[4][16][72];

  int qrow0 = b * 512 + qt * 64 + w * 16;
  const _Float16* Qp = qkv + (size_t)qrow0 * 3072 + h * 64;
  half8 qa[2];
#pragma unroll
  for (int ks = 0; ks < 2; ks++)
    qa[ks] = *(const half8*)(Qp + (size_t)arow * 3072 + ks * 32 + ag * 8);

  const _Float16* Kb = qkv + (size_t)(b * 512) * 3072 + 1024 + h * 64;
  const _Float16* Vb = VT + (size_t)bh * 64 * 512;

  int srow = lane >> 3;
  int sslot = (lane & 7) ^ srow;
  const _Float16* Ksrc0 = Kb + (size_t)(w * 16 + srow) * 3072 + sslot * 8;
  const _Float16* Vsrc0 = Vb + (size_t)(w * 16 + srow) * 512 + sslot * 8;

  int rs = arow & 7;

  float psl[4] = {0.f, 0.f, 0.f, 0.f};
  f32x4 oacc[4] = {};

  for (int st = 0; st < 8; ++st) {
#pragma unroll
    for (int i = 0; i < 2; i++) {
      gload16(Ksrc0 + (size_t)(st * 64 + i * 8) * 3072, &Ks[(w * 16 + i * 8) * 64]);
      gload16(Vsrc0 + (size_t)(i * 8) * 512 + st * 64,  &Vs[(w * 16 + i * 8) * 64]);
    }
    __syncthreads();

    f32x4 lg[4];
#pragma unroll
    for (int c = 0; c < 4; c++) {
      f32x4 a0 = {};
#pragma unroll
      for (int ks = 0; ks < 2; ks++) {
        int slot = (ks * 4 + ag) ^ rs;
        half8 kb = *(const half8*)&Ks[(c * 16 + arow) * 64 + slot * 8];
        a0 = __builtin_amdgcn_mfma_f32_16x16x32_f16(qa[ks], kb, a0, 0, 0, 0);
      }
      lg[c] = a0;
    }
    _Float16 ph[4][4];
#pragma unroll
    for (int r = 0; r < 4; r++) {
#pragma unroll
      for (int c = 0; c < 4; c++) {
        float p = __builtin_amdgcn_exp2f(lg[c][r] * 1.44269504f);
        psl[r] += p;
        ph[c][r] = (_Float16)p;
      }
    }
#pragma unroll
    for (int c = 0; c < 4; c++)
#pragma unroll
      for (int r = 0; r < 4; r++) Pl[w][ag * 4 + r][c * 16 + arow] = ph[c][r];
#pragma unroll
    for (int ks = 0; ks < 2; ks++) {
      half8 pa = *(const half8*)&Pl[w][arow][ks * 32 + ag * 8];
#pragma unroll
      for (int c = 0; c < 4; c++) {
        int slot = (ks * 4 + ag) ^ rs;
        half8 vb = *(const half8*)&Vs[(c * 16 + arow) * 64 + slot * 8];
        oacc[c] = __builtin_amdgcn_mfma_f32_16x16x32_f16(pa, vb, oacc[c], 0, 0, 0);
      }
    }
    __syncthreads();
  }
#pragma unroll
  for (int r = 0; r < 4; r++)
#pragma unroll
    for (int d = 1; d < 16; d <<= 1) psl[r] += __shfl_xor(psl[r], d, 16);
#pragma unroll
  for (int c = 0; c < 4; c++)
#pragma unroll
    for (int r = 0; r < 4; r++) {
      float v = oacc[c][r] / psl[r];
      out[(size_t)(qrow0 + ag * 4 + r) * 1024 + h * 64 + c * 16 + arow] = (_Float16)v;
    }
}

extern "C" void kernel_launch(void* const* d_in, const int* in_sizes, int n_in,
                              void* d_out, int out_size, void* d_ws, size_t ws_size,
                              hipStream_t stream) {
  const float* x  = (const float*)d_in[0];
  const float* Wq = (const float*)d_in[1];
  const float* bq = (const float*)d_in[2];
  const float* Wk = (const float*)d_in[3];
  const float* bk = (const float*)d_in[4];
  const float* Wv = (const float*)d_in[5];
  const float* bv = (const float*)d_in[6];
  const float* Wo = (const float*)d_in[7];
  const float* bo = (const float*)d_in[8];

  char* ws = (char*)d_ws;
  float2* cs      = (float2*)(ws + OFF_CS);
  _Float16* xh    = (_Float16*)(ws + OFF_XH);
  _Float16* wqkvt = (_Float16*)(ws + OFF_WQKVT);
  _Float16* wot   = (_Float16*)(ws + OFF_WOT);
  _Float16* qkv   = (_Float16*)(ws + OFF_QKV);
  _Float16* VT    = (_Float16*)(ws + OFF_VT);
  _Float16* attn  = (_Float16*)(ws + OFF_ATTN);

  rope_table_k<<<64, 256, 0, stream>>>(cs);
  convert_f16_k<<<4096, 256, 0, stream>>>(x, xh, 1048576);
  transpose4_k<<<dim3(32, 32, 4), dim3(32, 8), 0, stream>>>(Wq, Wk, Wv, Wo, wqkvt, wot);
  // qkv = fp16(x @ [Wq|Wk|Wv] + b), rope fused on q,k (q also x scale^2)
  gemm256_k<<<192, 512, 0, stream>>>(xh, wqkvt, bq, bk, bv, qkv, cs);
  vt_k<<<2048, 256, 0, stream>>>(qkv, VT);
  attn_k<<<1024, 256, 0, stream>>>(qkv, VT, attn);
  gemm_out_k<<<dim3(8, 32), 256, 0, stream>>>(attn, wot, bo, (float*)d_out);
}

// Round 6
// 107.510 us; speedup vs baseline: 1.1841x; 1.0994x over previous
//
#include <hip/hip_runtime.h>

typedef _Float16 half8 __attribute__((ext_vector_type(8)));
typedef _Float16 half4v __attribute__((ext_vector_type(4)));
typedef float f32x4 __attribute__((ext_vector_type(4)));

// Problem sizes (fixed): B=8, S=512, D=1024, H=16, HD=64; M = B*S = 4096
#define OFF_CS    0u
#define OFF_XH    (1u<<20)
#define OFF_WQKVT (OFF_XH + 8u*1024u*1024u)
#define OFF_WOT   (OFF_WQKVT + 8u*1024u*1024u)
#define OFF_QKV   (OFF_WOT + 2u*1024u*1024u)
#define OFF_VT    OFF_XH
#define OFF_ATTN  OFF_WQKVT

__device__ __forceinline__ void gload16(const _Float16* g, _Float16* l) {
  __builtin_amdgcn_global_load_lds((const __attribute__((address_space(1))) void*)g,
                                   (__attribute__((address_space(3))) void*)l, 16, 0, 0);
}

// ---- packed RoPE table: cs[pos*32+j] = (cos, sin) ----
__global__ void rope_table_k(float2* __restrict__ cs) {
  int idx = blockIdx.x * 256 + threadIdx.x;
  if (idx >= 512 * 32) return;
  int pos = idx >> 5, j = idx & 31;
  float inv = powf(10000.0f, -(float)j * (1.0f / 32.0f));
  float f = (float)pos * inv;
  cs[idx] = make_float2(cosf(f), sinf(f));
}

// ---- fp32 -> fp16 convert ----
__global__ void convert_f16_k(const float* __restrict__ in, _Float16* __restrict__ out, int n4) {
  int i = blockIdx.x * 256 + threadIdx.x;
  if (i >= n4) return;
  float4 v = ((const float4*)in)[i];
  half4v h;
  h[0] = (_Float16)v.x; h[1] = (_Float16)v.y; h[2] = (_Float16)v.z; h[3] = (_Float16)v.w;
  *(half4v*)(out + (size_t)i * 4) = h;
}

// ---- 4 weight transposes in one launch: W [k][n] f32 -> Wt [n][k] f16 ----
__global__ void transpose4_k(const float* __restrict__ W0, const float* __restrict__ W1,
                             const float* __restrict__ W2, const float* __restrict__ W3,
                             _Float16* __restrict__ dqkv, _Float16* __restrict__ dwo) {
  __shared__ float tile[32][33];
  int z = blockIdx.z;
  const float* W = z == 0 ? W0 : z == 1 ? W1 : z == 2 ? W2 : W3;
  _Float16* Wt = z < 3 ? dqkv + (size_t)z * 1048576 : dwo;
  int tx = threadIdx.x, ty = threadIdx.y;
  int bx = blockIdx.x, by = blockIdx.y;
#pragma unroll
  for (int i = 0; i < 4; i++)
    tile[ty + i * 8][tx] = W[(size_t)(by * 32 + ty + i * 8) * 1024 + bx * 32 + tx];
  __syncthreads();
#pragma unroll
  for (int i = 0; i < 4; i++)
    Wt[(size_t)(bx * 32 + ty + i * 8) * 1024 + by * 32 + tx] = (_Float16)tile[tx][ty + i * 8];
}

// ================= 256x256 fine-phase ring-4 GEMM (QKV + fused RoPE) =================
// BK=32, ring-4 slots (t&3), prefetch distance 3, vmcnt(8) only at tile close.
// Per tile: 2 phases of {ds_read subtile + 2 gload stage -> barrier -> lgkm(0) ->
// setprio 16 MFMA -> barrier}. Swizzle: row r slot s at elem (r>>1)*64 + s8*8,
// s8 = (((r&1)<<2)|ag) ^ ((r>>1)&7); inverse pre-applied at the global source.

// stage one 128-row half (8 KB) of an operand tile: 1 gload16/thread (512 thr)
__device__ __forceinline__ void stage_half(const _Float16* G, _Float16* L, int w, int lane) {
  int qq = (lane & 7) ^ (lane >> 3);
  int rloc = ((lane >> 3) << 1) + (qq >> 2);   // row within 16-row chunk
  int gcol = (qq & 3) * 8;                     // element column
  gload16(G + (size_t)(w * 16 + rloc) * 1024 + gcol, L + w * 512);
}

__global__ __launch_bounds__(512, 2) void gemm256_k(
    const _Float16* __restrict__ A, const _Float16* __restrict__ Bt,
    const float* __restrict__ b0, const float* __restrict__ b1, const float* __restrict__ b2,
    _Float16* __restrict__ C, const float2* __restrict__ cs) {
  __shared__ _Float16 Ar[4][256 * 32];  // 64 KiB
  __shared__ _Float16 Br[4][256 * 32];  // 64 KiB

  int bid = blockIdx.x;                       // 0..191
  int wgid = (bid & 7) * 24 + (bid >> 3);     // XCD-chunked (192 % 8 == 0 -> bijective)
  int by = wgid / 12, bx = wgid % 12;

  int tid = threadIdx.x, lane = tid & 63, w = tid >> 6;
  int wr = w >> 2, wc = w & 3;                // 2M x 4N waves; per-wave out 128x64
  int arow = lane & 15, ag = lane >> 4;
  int s8 = (((arow & 1) << 2) | ag) ^ ((arow >> 1) & 7);
  int rpA = wr * 64 + (arow >> 1);            // rowpair base for A frags
  int rpB = wc * 32 + (arow >> 1);            // rowpair base for B frags

  const _Float16* Agt = A + (size_t)(by * 256) * 1024;
  const _Float16* Bgt = Bt + (size_t)(bx * 256) * 1024;

  f32x4 acc[8][4] = {};

  // prologue: stage tiles 0,1,2 (4 loads/thread each)
#pragma unroll
  for (int t = 0; t < 3; ++t) {
    stage_half(Agt + t * 32,          &Ar[t][0],    w, lane);
    stage_half(Agt + t * 32 + 131072, &Ar[t][4096], w, lane);
    stage_half(Bgt + t * 32,          &Br[t][0],    w, lane);
    stage_half(Bgt + t * 32 + 131072, &Br[t][4096], w, lane);
  }
  asm volatile("s_waitcnt vmcnt(8)" ::: "memory");  // tile 0 landed (own loads)
  __builtin_amdgcn_s_barrier();                     // ...for ALL waves

  for (int t = 0; t < 32; ++t) {
    const _Float16* Ac = &Ar[t & 3][0];
    const _Float16* Bc = &Br[t & 3][0];
    half8 af[4], bf[4];
    // ---------- phase 0: B frags + A rows 0-63 of wave; stage A-halves of t+3 ----------
#pragma unroll
    for (int n = 0; n < 4; n++)
      bf[n] = *(const half8*)&Bc[(rpB + n * 8) * 64 + s8 * 8];
#pragma unroll
    for (int m = 0; m < 4; m++)
      af[m] = *(const half8*)&Ac[(rpA + m * 8) * 64 + s8 * 8];
    if (t < 29) {
      stage_half(Agt + (t + 3) * 32,          &Ar[(t + 3) & 3][0],    w, lane);
      stage_half(Agt + (t + 3) * 32 + 131072, &Ar[(t + 3) & 3][4096], w, lane);
    }
    __builtin_amdgcn_sched_barrier(0);
    __builtin_amdgcn_s_barrier();
    asm volatile("s_waitcnt lgkmcnt(0)" ::: "memory");
    __builtin_amdgcn_sched_barrier(0);
    __builtin_amdgcn_s_setprio(1);
#pragma unroll
    for (int m = 0; m < 4; m++)
#pragma unroll
      for (int n = 0; n < 4; n++)
        acc[m][n] = __builtin_amdgcn_mfma_f32_16x16x32_f16(af[m], bf[n], acc[m][n], 0, 0, 0);
    __builtin_amdgcn_s_setprio(0);
    __builtin_amdgcn_sched_barrier(0);
    __builtin_amdgcn_s_barrier();
    // ---------- phase 1: A rows 64-127 of wave; stage B-halves of t+3 ----------
#pragma unroll
    for (int m = 0; m < 4; m++)
      af[m] = *(const half8*)&Ac[(rpA + 32 + m * 8) * 64 + s8 * 8];
    if (t < 29) {
      stage_half(Bgt + (t + 3) * 32,          &Br[(t + 3) & 3][0],    w, lane);
      stage_half(Bgt + (t + 3) * 32 + 131072, &Br[(t + 3) & 3][4096], w, lane);
    }
    __builtin_amdgcn_sched_barrier(0);
    __builtin_amdgcn_s_barrier();
    asm volatile("s_waitcnt lgkmcnt(0)" ::: "memory");
    __builtin_amdgcn_sched_barrier(0);
    __builtin_amdgcn_s_setprio(1);
#pragma unroll
    for (int m = 0; m < 4; m++)
#pragma unroll
      for (int n = 0; n < 4; n++)
        acc[4 + m][n] = __builtin_amdgcn_mfma_f32_16x16x32_f16(af[m], bf[n], acc[4 + m][n], 0, 0, 0);
    __builtin_amdgcn_s_setprio(0);
    // counted tile-close wait: tile t+1 must be landed after the next barrier
    if (t <= 28)      asm volatile("s_waitcnt vmcnt(8)" ::: "memory");
    else if (t == 29) asm volatile("s_waitcnt vmcnt(4)" ::: "memory");
    else if (t == 30) asm volatile("s_waitcnt vmcnt(0)" ::: "memory");
    __builtin_amdgcn_sched_barrier(0);
    __builtin_amdgcn_s_barrier();
  }

  // ---- epilogue: bias + fp16 round (+ RoPE for q,k cols) ----
  int gc0 = bx * 256 + wc * 64;  // 64-aligned: wave entirely inside one q/k/v head-block
  const float* bp = gc0 < 1024 ? b0 : (gc0 < 2048 ? b1 : b2);
  float bb_[4];
#pragma unroll
  for (int n = 0; n < 4; n++) bb_[n] = bp[(gc0 & 1023) + n * 16 + arow];

  if (gc0 < 2048) {
    bool isQ = gc0 < 1024;
#pragma unroll
    for (int m = 0; m < 8; m++) {
      int gr = by * 256 + wr * 128 + m * 16 + ag * 4;
#pragma unroll
      for (int r = 0; r < 4; r++) {
        int row = gr + r, pos = row & 511;
#pragma unroll
        for (int n = 0; n < 2; n++) {
          int j = n * 16 + arow;
          float a = (float)(_Float16)(acc[m][n][r] + bb_[n]);
          float b = (float)(_Float16)(acc[m][n + 2][r] + bb_[n + 2]);
          float2 tt = cs[pos * 32 + j];
          float o0 = a * tt.x - b * tt.y;
          float o1 = b * tt.x + a * tt.y;
          if (isQ) { o0 *= 0.015625f; o1 *= 0.015625f; }  // scale^2 = 1/HD
          C[(size_t)row * 3072 + gc0 + j]      = (_Float16)o0;
          C[(size_t)row * 3072 + gc0 + j + 32] = (_Float16)o1;
        }
      }
    }
  } else {
#pragma unroll
    for (int m = 0; m < 8; m++) {
      int gr = by * 256 + wr * 128 + m * 16 + ag * 4;
#pragma unroll
      for (int n = 0; n < 4; n++)
#pragma unroll
        for (int r = 0; r < 4; r++)
          C[(size_t)(gr + r) * 3072 + gc0 + n * 16 + arow] = (_Float16)(acc[m][n][r] + bb_[n]);
    }
  }
}

// ---- output-proj GEMM (m97 structure): C_f32[4096x1024] = fp16round(A @ Wot^T + bo) ----
__global__ __launch_bounds__(256, 2) void gemm_out_k(
    const _Float16* __restrict__ A, const _Float16* __restrict__ Bt,
    const float* __restrict__ bo, float* __restrict__ Cv) {
  __shared__ _Float16 As[128 * 32];
  __shared__ _Float16 Bs[128 * 32];
  const int K = 1024, N = 1024;
  int bx = blockIdx.x, by = blockIdx.y;
  int tid = threadIdx.x, lane = tid & 63, w = tid >> 6;
  int wr = w >> 1, wc = w & 1;
  int arow = lane & 15, ag = lane >> 4;
  int lr = lane >> 2, lc = lane & 3;

  f32x4 acc[4][4] = {};

  for (int kt = 0; kt < 32; ++kt) {
    int k0 = kt * 32;
#pragma unroll
    for (int i = 0; i < 2; i++) {
      gload16(A  + (size_t)(by * 128 + w * 32 + i * 16 + lr) * K + k0 + lc * 8,
              &As[(w * 32 + i * 16) * 32]);
      gload16(Bt + (size_t)(bx * 128 + w * 32 + i * 16 + lr) * K + k0 + lc * 8,
              &Bs[(w * 32 + i * 16) * 32]);
    }
    __syncthreads();
    half8 a[4], b[4];
#pragma unroll
    for (int mi = 0; mi < 4; mi++)
      a[mi] = *(const half8*)&As[(wr * 64 + mi * 16 + arow) * 32 + ag * 8];
#pragma unroll
    for (int ni = 0; ni < 4; ni++)
      b[ni] = *(const half8*)&Bs[(wc * 64 + ni * 16 + arow) * 32 + ag * 8];
#pragma unroll
    for (int mi = 0; mi < 4; mi++)
#pragma unroll
      for (int ni = 0; ni < 4; ni++)
        acc[mi][ni] = __builtin_amdgcn_mfma_f32_16x16x32_f16(a[mi], b[ni], acc[mi][ni], 0, 0, 0);
    __syncthreads();
  }

#pragma unroll
  for (int mi = 0; mi < 4; mi++) {
    int gr = by * 128 + wr * 64 + mi * 16 + ag * 4;
#pragma unroll
    for (int ni = 0; ni < 4; ni++) {
      int gc = bx * 128 + wc * 64 + ni * 16 + arow;
      float bb = bo[gc];
#pragma unroll
      for (int r = 0; r < 4; r++)
        Cv[(size_t)(gr + r) * N + gc] = (float)(_Float16)(acc[mi][ni][r] + bb);
    }
  }
}

// ---- V^T via LDS tile transpose: qkv V-part [s][hd] -> VT[bh][hd][s], both sides 16B ----
__global__ void vt_k(const _Float16* __restrict__ qkv, _Float16* __restrict__ VT) {
  __shared__ _Float16 T[64][72];       // [s_local][hd], +8 pad
  int id = blockIdx.x;                 // 1024 = 8 sblk x 128 bh; id%8 = bh%8 (XCD-grouped)
  int bh = id & 127, sb = id >> 7;
  int b = bh >> 4, h = bh & 15;
  int tid = threadIdx.x;               // 256
  const _Float16* src = qkv + (size_t)(b * 512 + sb * 64) * 3072 + 2048 + h * 64;
#pragma unroll
  for (int i = 0; i < 2; i++) {
    int c = i * 256 + tid, r = c >> 3, cc = c & 7;
    *(half8*)&T[r][cc * 8] = *(const half8*)(src + (size_t)r * 3072 + cc * 8);
  }
  __syncthreads();
  _Float16* dst = VT + (size_t)bh * 64 * 512 + (size_t)sb * 64;
#pragma unroll
  for (int i = 0; i < 2; i++) {
    int c = i * 256 + tid, hd = c >> 3, sc = c & 7;
    half8 v;
#pragma unroll
    for (int j = 0; j < 8; j++) v[j] = T[sc * 8 + j][hd];
    *(half8*)(dst + (size_t)hd * 512 + sc * 8) = v;
  }
}

// ---- Fused attention (unchanged) ----
__global__ __launch_bounds__(256, 4) void attn_k(const _Float16* __restrict__ qkv,
                                                 const _Float16* __restrict__ VT,
                                                 _Float16* __restrict__ out) {
  int id = blockIdx.x;
  int bh = id & 127, qt = id >> 7;
  int b = bh >> 4, h = bh & 15;
  int tid = threadIdx.x, lane = tid & 63, w = tid >> 6;
  int arow = lane & 15, ag = lane >> 4;

  __shared__ _Float16 Ks[64 * 64];
  __shared__ _Float16 Vs[64 * 64];
  __shared__ _Float16 Pl[4][16][72];

  int qrow0 = b * 512 + qt * 64 + w * 16;
  const _Float16* Qp = qkv + (size_t)qrow0 * 3072 + h * 64;
  half8 qa[2];
#pragma unroll
  for (int ks = 0; ks < 2; ks++)
    qa[ks] = *(const half8*)(Qp + (size_t)arow * 3072 + ks * 32 + ag * 8);

  const _Float16* Kb = qkv + (size_t)(b * 512) * 3072 + 1024 + h * 64;
  const _Float16* Vb = VT + (size_t)bh * 64 * 512;

  int srow = lane >> 3;
  int sslot = (lane & 7) ^ srow;
  const _Float16* Ksrc0 = Kb + (size_t)(w * 16 + srow) * 3072 + sslot * 8;
  const _Float16* Vsrc0 = Vb + (size_t)(w * 16 + srow) * 512 + sslot * 8;

  int rs = arow & 7;

  float psl[4] = {0.f, 0.f, 0.f, 0.f};
  f32x4 oacc[4] = {};

  for (int st = 0; st < 8; ++st) {
#pragma unroll
    for (int i = 0; i < 2; i++) {
      gload16(Ksrc0 + (size_t)(st * 64 + i * 8) * 3072, &Ks[(w * 16 + i * 8) * 64]);
      gload16(Vsrc0 + (size_t)(i * 8) * 512 + st * 64,  &Vs[(w * 16 + i * 8) * 64]);
    }
    __syncthreads();

    f32x4 lg[4];
#pragma unroll
    for (int c = 0; c < 4; c++) {
      f32x4 a0 = {};
#pragma unroll
      for (int ks = 0; ks < 2; ks++) {
        int slot = (ks * 4 + ag) ^ rs;
        half8 kb = *(const half8*)&Ks[(c * 16 + arow) * 64 + slot * 8];
        a0 = __builtin_amdgcn_mfma_f32_16x16x32_f16(qa[ks], kb, a0, 0, 0, 0);
      }
      lg[c] = a0;
    }
    _Float16 ph[4][4];
#pragma unroll
    for (int r = 0; r < 4; r++) {
#pragma unroll
      for (int c = 0; c < 4; c++) {
        float p = __builtin_amdgcn_exp2f(lg[c][r] * 1.44269504f);
        psl[r] += p;
        ph[c][r] = (_Float16)p;
      }
    }
#pragma unroll
    for (int c = 0; c < 4; c++)
#pragma unroll
      for (int r = 0; r < 4; r++) Pl[w][ag * 4 + r][c * 16 + arow] = ph[c][r];
#pragma unroll
    for (int ks = 0; ks < 2; ks++) {
      half8 pa = *(const half8*)&Pl[w][arow][ks * 32 + ag * 8];
#pragma unroll
      for (int c = 0; c < 4; c++) {
        int slot = (ks * 4 + ag) ^ rs;
        half8 vb = *(const half8*)&Vs[(c * 16 + arow) * 64 + slot * 8];
        oacc[c] = __builtin_amdgcn_mfma_f32_16x16x32_f16(pa, vb, oacc[c], 0, 0, 0);
      }
    }
    __syncthreads();
  }
#pragma unroll
  for (int r = 0; r < 4; r++)
#pragma unroll
    for (int d = 1; d < 16; d <<= 1) psl[r] += __shfl_xor(psl[r], d, 16);
#pragma unroll
  for (int c = 0; c < 4; c++)
#pragma unroll
    for (int r = 0; r < 4; r++) {
      float v = oacc[c][r] / psl[r];
      out[(size_t)(qrow0 + ag * 4 + r) * 1024 + h * 64 + c * 16 + arow] = (_Float16)v;
    }
}

extern "C" void kernel_launch(void* const* d_in, const int* in_sizes, int n_in,
                              void* d_out, int out_size, void* d_ws, size_t ws_size,
                              hipStream_t stream) {
  const float* x  = (const float*)d_in[0];
  const float* Wq = (const float*)d_in[1];
  const float* bq = (const float*)d_in[2];
  const float* Wk = (const float*)d_in[3];
  const float* bk = (const float*)d_in[4];
  const float* Wv = (const float*)d_in[5];
  const float* bv = (const float*)d_in[6];
  const float* Wo = (const float*)d_in[7];
  const float* bo = (const float*)d_in[8];

  char* ws = (char*)d_ws;
  float2* cs      = (float2*)(ws + OFF_CS);
  _Float16* xh    = (_Float16*)(ws + OFF_XH);
  _Float16* wqkvt = (_Float16*)(ws + OFF_WQKVT);
  _Float16* wot   = (_Float16*)(ws + OFF_WOT);
  _Float16* qkv   = (_Float16*)(ws + OFF_QKV);
  _Float16* VT    = (_Float16*)(ws + OFF_VT);
  _Float16* attn  = (_Float16*)(ws + OFF_ATTN);

  rope_table_k<<<64, 256, 0, stream>>>(cs);
  convert_f16_k<<<4096, 256, 0, stream>>>(x, xh, 1048576);
  transpose4_k<<<dim3(32, 32, 4), dim3(32, 8), 0, stream>>>(Wq, Wk, Wv, Wo, wqkvt, wot);
  gemm256_k<<<192, 512, 0, stream>>>(xh, wqkvt, bq, bk, bv, qkv, cs);
  vt_k<<<1024, 256, 0, stream>>>(qkv, VT);
  attn_k<<<1024, 256, 0, stream>>>(qkv, VT, attn);
  gemm_out_k<<<dim3(8, 32), 256, 0, stream>>>(attn, wot, bo, (float*)d_out);
}

// Round 7
// 96.875 us; speedup vs baseline: 1.3141x; 1.1098x over previous
//
#include <hip/hip_runtime.h>

typedef _Float16 half8 __attribute__((ext_vector_type(8)));
typedef _Float16 half4v __attribute__((ext_vector_type(4)));
typedef float f32x4 __attribute__((ext_vector_type(4)));

// Problem sizes (fixed): B=8, S=512, D=1024, H=16, HD=64; M = B*S = 4096
#define OFF_CS    0u
#define OFF_XH    (1u<<20)
#define OFF_WQKVT (OFF_XH + 8u*1024u*1024u)
#define OFF_WOT   (OFF_WQKVT + 8u*1024u*1024u)
#define OFF_QKV   (OFF_WOT + 2u*1024u*1024u)
#define OFF_VT    OFF_XH
#define OFF_ATTN  OFF_WQKVT

__device__ __forceinline__ void gload16(const _Float16* g, _Float16* l) {
  __builtin_amdgcn_global_load_lds((const __attribute__((address_space(1))) void*)g,
                                   (__attribute__((address_space(3))) void*)l, 16, 0, 0);
}

// ---- fused prep: x->fp16 convert | 4 weight transposes | rope table ----
__global__ void prep_k(const float* __restrict__ x,
                       const float* __restrict__ W0, const float* __restrict__ W1,
                       const float* __restrict__ W2, const float* __restrict__ W3,
                       _Float16* __restrict__ xh, _Float16* __restrict__ wqkvt,
                       _Float16* __restrict__ wot, float2* __restrict__ cs) {
  int bid = blockIdx.x, tid = threadIdx.x;
  if (bid < 4096) {                       // convert: 4096 blocks x 256 thr x 1 float4
    int i = bid * 256 + tid;
    float4 v = ((const float4*)x)[i];
    half4v h;
    h[0] = (_Float16)v.x; h[1] = (_Float16)v.y; h[2] = (_Float16)v.z; h[3] = (_Float16)v.w;
    *(half4v*)(xh + (size_t)i * 4) = h;
  } else if (bid < 8192) {                // transpose: 4 x 1024 blocks, one 32x32 tile each
    __shared__ float tile[32][33];
    int tb = bid - 4096;
    int z = tb >> 10, t = tb & 1023, by = t >> 5, bx = t & 31;
    const float* W = z == 0 ? W0 : z == 1 ? W1 : z == 2 ? W2 : W3;
    _Float16* Wt = z < 3 ? wqkvt + (size_t)z * 1048576 : wot;
    int r = tid >> 3, c0 = (tid & 7) * 4;
    float4 v = *(const float4*)(W + (size_t)(by * 32 + r) * 1024 + bx * 32 + c0);
    tile[r][c0] = v.x; tile[r][c0 + 1] = v.y; tile[r][c0 + 2] = v.z; tile[r][c0 + 3] = v.w;
    __syncthreads();
    half4v h;
#pragma unroll
    for (int j = 0; j < 4; j++) h[j] = (_Float16)tile[c0 + j][r];
    *(half4v*)(Wt + (size_t)(bx * 32 + r) * 1024 + by * 32 + c0) = h;
  } else {                                // rope table: 64 blocks
    int idx = (bid - 8192) * 256 + tid;
    int pos = idx >> 5, j = idx & 31;
    float inv = powf(10000.0f, -(float)j * (1.0f / 32.0f));
    float f = (float)pos * inv;
    cs[idx] = make_float2(cosf(f), sinf(f));
  }
}

// ================= 128x128 2-phase ping-pong GEMM (m97 geometry + swizzle) =================
// BK=32, 4 waves (2x2), per-wave 64x64. Stage(t+1) issued BEFORE compute(t) (T3-minimum:
// loads fly under ds_read+MFMA), ONE __syncthreads per K-step (drains vmcnt+lgkm).
// LDS swizzle (verified 0-conflict in r5/r6): row-pair layout, elem (R>>1)*64 + s8*8,
// s8 = (((R&1)<<2)|slot) ^ ((R>>1)&7); inverse pre-applied at the global source.
// MODE 0: N=3072 qkv out fp16 + fused RoPE (q also x scale^2=1/64). MODE 1: N=1024, f32 out.
template <int MODE>
__global__ __launch_bounds__(256, 3) void gemm128_k(
    const _Float16* __restrict__ A, const _Float16* __restrict__ Bt,
    const float* __restrict__ b0, const float* __restrict__ b1, const float* __restrict__ b2,
    void* __restrict__ Cv, const float2* __restrict__ cs) {
  const int K = 1024;
  const int N = (MODE == 0) ? 3072 : 1024;
  const int NBX = N / 128;
  __shared__ _Float16 Ab[2][128 * 32];  // 8 KB each
  __shared__ _Float16 Bb[2][128 * 32];

  int nwg = gridDim.x, cpx = nwg >> 3;
  int bid = blockIdx.x;
  int wgid = (bid & 7) * cpx + (bid >> 3);   // XCD-chunked (nwg % 8 == 0 -> bijective)
  int by = wgid / NBX, bx = wgid % NBX;

  int tid = threadIdx.x, lane = tid & 63, w = tid >> 6;
  int wr = w >> 1, wc = w & 1;
  int arow = lane & 15, ag = lane >> 4;
  int s8 = (((arow & 1) << 2) | ag) ^ ((arow >> 1) & 7);

  // staging lane -> (row-in-chunk, col) with inverse swizzle (rule 21)
  int qq = (lane & 7) ^ (lane >> 3);
  int rloc = ((lane >> 3) << 1) + (qq >> 2);
  int gcol = (qq & 3) * 8;

  const _Float16* Ag = A + (size_t)(by * 128) * K;
  const _Float16* Bg = Bt + (size_t)(bx * 128) * K;

  f32x4 acc[4][4] = {};

  // prologue: stage tile 0 -> buf 0
  {
    int k0 = 0;
#pragma unroll
    for (int i = 0; i < 2; i++) {
      int c = w * 2 + i;
      gload16(Ag + (size_t)(c * 16 + rloc) * K + k0 + gcol, &Ab[0][c * 512]);
      gload16(Bg + (size_t)(c * 16 + rloc) * K + k0 + gcol, &Bb[0][c * 512]);
    }
  }
  __syncthreads();

  for (int t = 0; t < 32; ++t) {
    int cur = t & 1;
    if (t < 31) {  // stage t+1 early: overlaps the ds_read+MFMA below
      int k0 = (t + 1) * 32;
#pragma unroll
      for (int i = 0; i < 2; i++) {
        int c = w * 2 + i;
        gload16(Ag + (size_t)(c * 16 + rloc) * K + k0 + gcol, &Ab[cur ^ 1][c * 512]);
        gload16(Bg + (size_t)(c * 16 + rloc) * K + k0 + gcol, &Bb[cur ^ 1][c * 512]);
      }
    }
    __builtin_amdgcn_sched_barrier(0);  // keep stage issues above the reads
    const _Float16* Ac = &Ab[cur][0];
    const _Float16* Bc = &Bb[cur][0];
    half8 a[4], b[4];
#pragma unroll
    for (int m = 0; m < 4; m++) {
      int R = wr * 64 + m * 16 + arow;
      a[m] = *(const half8*)&Ac[(R >> 1) * 64 + s8 * 8];
    }
#pragma unroll
    for (int n = 0; n < 4; n++) {
      int R = wc * 64 + n * 16 + arow;
      b[n] = *(const half8*)&Bc[(R >> 1) * 64 + s8 * 8];
    }
#pragma unroll
    for (int m = 0; m < 4; m++)
#pragma unroll
      for (int n = 0; n < 4; n++)
        acc[m][n] = __builtin_amdgcn_mfma_f32_16x16x32_f16(a[m], b[n], acc[m][n], 0, 0, 0);
    __syncthreads();  // drains vmcnt(0)+lgkm(0): tile t+1 visible, WAR cleared
  }

  // ---- epilogue ----
  int gc0 = bx * 128 + wc * 64;  // 64-aligned -> wave inside one q/k/v head-block
  if (MODE == 0) {
    const float* bp = gc0 < 1024 ? b0 : (gc0 < 2048 ? b1 : b2);
    float bb_[4];
#pragma unroll
    for (int n = 0; n < 4; n++) bb_[n] = bp[(gc0 & 1023) + n * 16 + arow];
    _Float16* C = (_Float16*)Cv;
    if (gc0 < 2048) {  // fused RoPE on q,k: pair cols (j, j+32) = (n, n+2) in-thread
      bool isQ = gc0 < 1024;
#pragma unroll
      for (int m = 0; m < 4; m++) {
        int gr = by * 128 + wr * 64 + m * 16 + ag * 4;
#pragma unroll
        for (int r = 0; r < 4; r++) {
          int row = gr + r, pos = row & 511;
#pragma unroll
          for (int n = 0; n < 2; n++) {
            int j = n * 16 + arow;
            float av = (float)(_Float16)(acc[m][n][r] + bb_[n]);
            float bv = (float)(_Float16)(acc[m][n + 2][r] + bb_[n + 2]);
            float2 tt = cs[pos * 32 + j];
            float o0 = av * tt.x - bv * tt.y;
            float o1 = bv * tt.x + av * tt.y;
            if (isQ) { o0 *= 0.015625f; o1 *= 0.015625f; }  // scale^2 = 1/HD
            C[(size_t)row * 3072 + gc0 + j]      = (_Float16)o0;
            C[(size_t)row * 3072 + gc0 + j + 32] = (_Float16)o1;
          }
        }
      }
    } else {
#pragma unroll
      for (int m = 0; m < 4; m++) {
        int gr = by * 128 + wr * 64 + m * 16 + ag * 4;
#pragma unroll
        for (int n = 0; n < 4; n++)
#pragma unroll
          for (int r = 0; r < 4; r++)
            C[(size_t)(gr + r) * 3072 + gc0 + n * 16 + arow] = (_Float16)(acc[m][n][r] + bb_[n]);
      }
    }
  } else {
    float* C = (float*)Cv;
#pragma unroll
    for (int m = 0; m < 4; m++) {
      int gr = by * 128 + wr * 64 + m * 16 + ag * 4;
#pragma unroll
      for (int n = 0; n < 4; n++) {
        int gc = gc0 + n * 16 + arow;
        float bb = b0[gc];
#pragma unroll
        for (int r = 0; r < 4; r++)
          C[(size_t)(gr + r) * 1024 + gc] = (float)(_Float16)(acc[m][n][r] + bb);
      }
    }
  }
}

// ---- V^T via LDS tile transpose: qkv V-part [s][hd] -> VT[bh][hd][s], both sides 16B ----
__global__ void vt_k(const _Float16* __restrict__ qkv, _Float16* __restrict__ VT) {
  __shared__ _Float16 T[64][72];       // [s_local][hd], +8 pad
  int id = blockIdx.x;                 // 1024 = 8 sblk x 128 bh; id%8 = bh%8 (XCD-grouped)
  int bh = id & 127, sb = id >> 7;
  int b = bh >> 4, h = bh & 15;
  int tid = threadIdx.x;               // 256
  const _Float16* src = qkv + (size_t)(b * 512 + sb * 64) * 3072 + 2048 + h * 64;
#pragma unroll
  for (int i = 0; i < 2; i++) {
    int c = i * 256 + tid, r = c >> 3, cc = c & 7;
    *(half8*)&T[r][cc * 8] = *(const half8*)(src + (size_t)r * 3072 + cc * 8);
  }
  __syncthreads();
  _Float16* dst = VT + (size_t)bh * 64 * 512 + (size_t)sb * 64;
#pragma unroll
  for (int i = 0; i < 2; i++) {
    int c = i * 256 + tid, hd = c >> 3, sc = c & 7;
    half8 v;
#pragma unroll
    for (int j = 0; j < 8; j++) v[j] = T[sc * 8 + j][hd];
    *(half8*)(dst + (size_t)hd * 512 + sc * 8) = v;
  }
}

// ---- Fused attention (unchanged from round 3/6) ----
__global__ __launch_bounds__(256, 4) void attn_k(const _Float16* __restrict__ qkv,
                                                 const _Float16* __restrict__ VT,
                                                 _Float16* __restrict__ out) {
  int id = blockIdx.x;
  int bh = id & 127, qt = id >> 7;
  int b = bh >> 4, h = bh & 15;
  int tid = threadIdx.x, lane = tid & 63, w = tid >> 6;
  int arow = lane & 15, ag = lane >> 4;

  __shared__ _Float16 Ks[64 * 64];
  __shared__ _Float16 Vs[64 * 64];
  __shared__ _Float16 Pl[4][16][72];

  int qrow0 = b * 512 + qt * 64 + w * 16;
  const _Float16* Qp = qkv + (size_t)qrow0 * 3072 + h * 64;
  half8 qa[2];
#pragma unroll
  for (int ks = 0; ks < 2; ks++)
    qa[ks] = *(const half8*)(Qp + (size_t)arow * 3072 + ks * 32 + ag * 8);

  const _Float16* Kb = qkv + (size_t)(b * 512) * 3072 + 1024 + h * 64;
  const _Float16* Vb = VT + (size_t)bh * 64 * 512;

  int srow = lane >> 3;
  int sslot = (lane & 7) ^ srow;
  const _Float16* Ksrc0 = Kb + (size_t)(w * 16 + srow) * 3072 + sslot * 8;
  const _Float16* Vsrc0 = Vb + (size_t)(w * 16 + srow) * 512 + sslot * 8;

  int rs = arow & 7;

  float psl[4] = {0.f, 0.f, 0.f, 0.f};
  f32x4 oacc[4] = {};

  for (int st = 0; st < 8; ++st) {
#pragma unroll
    for (int i = 0; i < 2; i++) {
      gload16(Ksrc0 + (size_t)(st * 64 + i * 8) * 3072, &Ks[(w * 16 + i * 8) * 64]);
      gload16(Vsrc0 + (size_t)(i * 8) * 512 + st * 64,  &Vs[(w * 16 + i * 8) * 64]);
    }
    __syncthreads();

    f32x4 lg[4];
#pragma unroll
    for (int c = 0; c < 4; c++) {
      f32x4 a0 = {};
#pragma unroll
      for (int ks = 0; ks < 2; ks++) {
        int slot = (ks * 4 + ag) ^ rs;
        half8 kb = *(const half8*)&Ks[(c * 16 + arow) * 64 + slot * 8];
        a0 = __builtin_amdgcn_mfma_f32_16x16x32_f16(qa[ks], kb, a0, 0, 0, 0);
      }
      lg[c] = a0;
    }
    _Float16 ph[4][4];
#pragma unroll
    for (int r = 0; r < 4; r++) {
#pragma unroll
      for (int c = 0; c < 4; c++) {
        float p = __builtin_amdgcn_exp2f(lg[c][r] * 1.44269504f);
        psl[r] += p;
        ph[c][r] = (_Float16)p;
      }
    }
#pragma unroll
    for (int c = 0; c < 4; c++)
#pragma unroll
      for (int r = 0; r < 4; r++) Pl[w][ag * 4 + r][c * 16 + arow] = ph[c][r];
#pragma unroll
    for (int ks = 0; ks < 2; ks++) {
      half8 pa = *(const half8*)&Pl[w][arow][ks * 32 + ag * 8];
#pragma unroll
      for (int c = 0; c < 4; c++) {
        int slot = (ks * 4 + ag) ^ rs;
        half8 vb = *(const half8*)&Vs[(c * 16 + arow) * 64 + slot * 8];
        oacc[c] = __builtin_amdgcn_mfma_f32_16x16x32_f16(pa, vb, oacc[c], 0, 0, 0);
      }
    }
    __syncthreads();
  }
#pragma unroll
  for (int r = 0; r < 4; r++)
#pragma unroll
    for (int d = 1; d < 16; d <<= 1) psl[r] += __shfl_xor(psl[r], d, 16);
#pragma unroll
  for (int c = 0; c < 4; c++)
#pragma unroll
    for (int r = 0; r < 4; r++) {
      float v = oacc[c][r] / psl[r];
      out[(size_t)(qrow0 + ag * 4 + r) * 1024 + h * 64 + c * 16 + arow] = (_Float16)v;
    }
}

extern "C" void kernel_launch(void* const* d_in, const int* in_sizes, int n_in,
                              void* d_out, int out_size, void* d_ws, size_t ws_size,
                              hipStream_t stream) {
  const float* x  = (const float*)d_in[0];
  const float* Wq = (const float*)d_in[1];
  const float* bq = (const float*)d_in[2];
  const float* Wk = (const float*)d_in[3];
  const float* bk = (const float*)d_in[4];
  const float* Wv = (const float*)d_in[5];
  const float* bv = (const float*)d_in[6];
  const float* Wo = (const float*)d_in[7];
  const float* bo = (const float*)d_in[8];

  char* ws = (char*)d_ws;
  float2* cs      = (float2*)(ws + OFF_CS);
  _Float16* xh    = (_Float16*)(ws + OFF_XH);
  _Float16* wqkvt = (_Float16*)(ws + OFF_WQKVT);
  _Float16* wot   = (_Float16*)(ws + OFF_WOT);
  _Float16* qkv   = (_Float16*)(ws + OFF_QKV);
  _Float16* VT    = (_Float16*)(ws + OFF_VT);
  _Float16* attn  = (_Float16*)(ws + OFF_ATTN);

  // prep: convert + 4 transposes + rope table in one launch
  prep_k<<<8256, 256, 0, stream>>>(x, Wq, Wk, Wv, Wo, xh, wqkvt, wot, cs);
  // qkv = fp16(x @ [Wq|Wk|Wv] + b), rope fused on q,k (q also x scale^2)
  gemm128_k<0><<<768, 256, 0, stream>>>(xh, wqkvt, bq, bk, bv, qkv, cs);
  vt_k<<<1024, 256, 0, stream>>>(qkv, VT);
  attn_k<<<1024, 256, 0, stream>>>(qkv, VT, attn);
  // out = fp16(attn @ Wo + bo) stored as f32
  gemm128_k<1><<<256, 256, 0, stream>>>(attn, wot, bo, bo, bo, d_out, cs);
}